// Round 11
// baseline (8615.913 us; speedup 1.0000x reference)
//
#include <hip/hip_runtime.h>
#include <hip/hip_bf16.h>

#define D_  768
#define B_  1024
#define N_  50000
#define K_  10
#define CH_ 3125
#define NCH_ 16
#define CM_ 24

__device__ __forceinline__ float gelu_f(float x){ return 0.5f*x*(1.0f+erff(x*0.70710678118654752f)); }
__device__ __forceinline__ double gelu_d(double x){ return 0.5*x*(1.0+erf(x*0.707106781186547524400844362105)); }

__device__ __forceinline__ float block_sum(float v, float* sm){
  #pragma unroll
  for (int o=32;o>0;o>>=1) v += __shfl_xor(v,o);
  __syncthreads();
  if ((threadIdx.x&63)==0) sm[threadIdx.x>>6]=v;
  __syncthreads();
  return (sm[0]+sm[1])+(sm[2]+sm[3]);
}
__device__ __forceinline__ double block_sum64(double v, double* sm){
  #pragma unroll
  for (int o=32;o>0;o>>=1) v += __shfl_xor(v,o);
  __syncthreads();
  if ((threadIdx.x&63)==0) sm[threadIdx.x>>6]=v;
  __syncthreads();
  return (sm[0]+sm[1])+(sm[2]+sm[3]);
}

// ============ f64 tiled GEMM (stage A/B only): C = A @ W^T (+bias) ============
template<int ASRC, int EPI>
__global__ __launch_bounds__(256)
void dgemm_k(const void* __restrict__ Ap, const float* __restrict__ Wp, size_t woff,
             const float* __restrict__ biasp, size_t boff, double* __restrict__ Cp,
             int M, int N, int Kd, int ldc)
{
  __shared__ double As[16][64];
  __shared__ double Bs[16][64];
  const int t  = threadIdx.x;
  const int tx = t & 15, ty = t >> 4;
  const int row0 = blockIdx.y << 6, col0 = blockIdx.x << 6;
  const int lr = t >> 2, lk = (t & 3) << 2;
  const int ar = row0 + lr;
  const int wn = col0 + lr;
  const float* Wf = Wp + woff;
  double acc[4][4] = {};
  for (int k0 = 0; k0 < Kd; k0 += 16) {
    double av[4], wv[4];
    if (ar < M) {
      if (ASRC==0){
        const double* a = (const double*)Ap + (size_t)ar*Kd + k0 + lk;
        av[0]=a[0]; av[1]=a[1]; av[2]=a[2]; av[3]=a[3];
      } else {
        float4 v = *(const float4*)((const float*)Ap + (size_t)ar*Kd + k0 + lk);
        av[0]=(double)v.x; av[1]=(double)v.y; av[2]=(double)v.z; av[3]=(double)v.w;
      }
    } else { av[0]=av[1]=av[2]=av[3]=0.0; }
    if (wn < N) {
      float4 v = *(const float4*)(Wf + (size_t)wn*Kd + k0 + lk);
      wv[0]=(double)v.x; wv[1]=(double)v.y; wv[2]=(double)v.z; wv[3]=(double)v.w;
    } else { wv[0]=wv[1]=wv[2]=wv[3]=0.0; }
    #pragma unroll
    for (int u=0;u<4;++u){ As[lk+u][lr]=av[u]; Bs[lk+u][lr]=wv[u]; }
    __syncthreads();
    #pragma unroll
    for (int kk=0;kk<16;++kk){
      double aa[4], bb[4];
      #pragma unroll
      for (int u=0;u<4;++u){ aa[u]=As[kk][(ty<<2)+u]; bb[u]=Bs[kk][(tx<<2)+u]; }
      #pragma unroll
      for (int i=0;i<4;++i)
        #pragma unroll
        for (int j=0;j<4;++j)
          acc[i][j] = fma(aa[i], bb[j], acc[i][j]);
    }
    __syncthreads();
  }
  #pragma unroll
  for (int i=0;i<4;++i){
    int r=row0+(ty<<2)+i; if (r>=M) continue;
    #pragma unroll
    for (int j=0;j<4;++j){
      int n=col0+(tx<<2)+j; if (n>=N) continue;
      double v=acc[i][j];
      if (EPI) v += (double)(biasp+boff)[n];
      Cp[(size_t)r*ldc+n]=v;
    }
  }
}

// f64 LN + gelu (stage B)
__global__ __launch_bounds__(256)
void ln64_k(const double* __restrict__ x0, const float* __restrict__ g,
            const float* __restrict__ b, double* __restrict__ y)
{
  __shared__ double sm[4];
  size_t base = (size_t)blockIdx.x * D_;
  double xv[3]; double s=0.0;
  #pragma unroll
  for (int i=0;i<3;++i){ int c=threadIdx.x+(i<<8); xv[i]=x0[base+c]; s+=xv[i]; }
  s = block_sum64(s, sm);
  double m = s*(1.0/768.0);
  double vs=0.0;
  #pragma unroll
  for (int i=0;i<3;++i){ double d=xv[i]-m; vs+=d*d; }
  vs = block_sum64(vs, sm);
  double inv = 1.0/sqrt(vs*(1.0/768.0)+1e-5);
  #pragma unroll
  for (int i=0;i<3;++i){
    int c=threadIdx.x+(i<<8);
    double o=(xv[i]-m)*inv*(double)g[c]+(double)b[c];
    y[base+c]=gelu_d(o);
  }
}

// f64 inverse row norm.  SRC: 0 f64 ws, 1 f32 d_in.
template<int SRC>
__global__ __launch_bounds__(256)
void rnorm64_k(const void* __restrict__ x, double* __restrict__ invn)
{
  __shared__ double sm[4];
  size_t base=(size_t)blockIdx.x*D_;
  double s=0.0;
  for (int i=threadIdx.x;i<D_;i+=256){
    double v = (SRC==0) ? ((const double*)x)[base+i] : (double)((const float*)x)[base+i];
    s=fma(v,v,s);
  }
  s=block_sum64(s,sm);
  if (threadIdx.x==0) invn[blockIdx.x]=1.0/fmax(sqrt(s),1e-12);
}

__global__ void d2f_k(const double* __restrict__ src, float* __restrict__ dst, int n)
{ int i=blockIdx.x*256+threadIdx.x; if (i<n) dst[i]=(float)src[i]; }

__global__ void prep64_k(const float* __restrict__ vis, double* __restrict__ fusedin)
{
  int i = blockIdx.x*256+threadIdx.x;
  if (i >= B_*D_) return;
  int r=i/D_, c=i-r*D_;
  fusedin[(size_t)r*(2*D_)+c]=(double)vis[i];
}

// ============ f32 tiled GEMM ============
// ATY: 0 = A ws f32; 2 = A d_in f32; 3 = A d_in f32 with row gather.
// EPI: 0 none, 1 +bias, 2 +bias+gelu.  SCALE: epilogue ×inva32[r]×invw32[n].
template<int ATY, int EPI, int SCALE>
__global__ __launch_bounds__(256)
void gemm_k(const float* __restrict__ Ap, const int* __restrict__ ridx,
            const float* __restrict__ Wp, size_t woff,
            const float* __restrict__ biasp, size_t boff, float* __restrict__ Cp,
            const float* __restrict__ inva32, const float* __restrict__ invw32,
            int M, int N, int Kd, int ldc)
{
  __shared__ __align__(16) float As[16][64];
  __shared__ __align__(16) float Bs[16][64];
  const int t  = threadIdx.x;
  const int tx = t & 15, ty = t >> 4;
  const int row0 = blockIdx.y << 6, col0 = blockIdx.x << 6;
  const int lr = t >> 2, lk = (t & 3) << 2;
  const int ar = row0 + lr;
  const int wn = col0 + lr;
  const float* Wf = Wp + woff;
  float acc[4][4] = {};
  int arow = ar;
  if (ATY==3 && ar < M){
    arow = ridx[ar];
    if ((unsigned)arow >= (unsigned)N_) arow = 0;
  }
  for (int k0 = 0; k0 < Kd; k0 += 16) {
    float av[4], wv[4];
    if (ar < M) {
      float4 v = *(const float4*)(Ap + (size_t)arow*Kd + k0 + lk);
      av[0]=v.x; av[1]=v.y; av[2]=v.z; av[3]=v.w;
    } else { av[0]=av[1]=av[2]=av[3]=0.f; }
    if (wn < N) {
      float4 v = *(const float4*)(Wf + (size_t)wn*Kd + k0 + lk);
      wv[0]=v.x; wv[1]=v.y; wv[2]=v.z; wv[3]=v.w;
    } else { wv[0]=wv[1]=wv[2]=wv[3]=0.f; }
    #pragma unroll
    for (int u=0;u<4;++u){ As[lk+u][lr]=av[u]; Bs[lk+u][lr]=wv[u]; }
    __syncthreads();
    #pragma unroll
    for (int kk=0;kk<16;++kk){
      float4 a4 = *(const float4*)&As[kk][ty<<2];
      float4 b4 = *(const float4*)&Bs[kk][tx<<2];
      float aa[4]={a4.x,a4.y,a4.z,a4.w};
      float bb[4]={b4.x,b4.y,b4.z,b4.w};
      #pragma unroll
      for (int i=0;i<4;++i)
        #pragma unroll
        for (int j=0;j<4;++j)
          acc[i][j] = fmaf(aa[i], bb[j], acc[i][j]);
    }
    __syncthreads();
  }
  float bv[4];
  #pragma unroll
  for (int j=0;j<4;++j){
    int n=col0+(tx<<2)+j;
    bv[j] = (EPI>=1 && n<N) ? (biasp+boff)[n] : 0.f;
  }
  #pragma unroll
  for (int i=0;i<4;++i){
    int r=row0+(ty<<2)+i; if (r>=M) continue;
    float ia = (SCALE && r<M) ? inva32[r] : 1.f;
    #pragma unroll
    for (int j=0;j<4;++j){
      int n=col0+(tx<<2)+j; if (n>=N) continue;
      float v=acc[i][j]+bv[j];
      if (EPI==2) v=gelu_f(v);
      if (SCALE) v = v * ia * invw32[n];
      Cp[(size_t)r*ldc+n]=v;
    }
  }
}

// f32 LN
template<int RES>
__global__ __launch_bounds__(256)
void ln_k(const float* __restrict__ x0, const float* __restrict__ resf,
          const float* __restrict__ resb,
          const float* __restrict__ g, const float* __restrict__ b, size_t gboff,
          float* __restrict__ y)
{
  __shared__ float sm[4];
  size_t base = (size_t)blockIdx.x * D_;
  float xv[3]; float s=0.f;
  #pragma unroll
  for (int i=0;i<3;++i){
    int c=threadIdx.x+(i<<8);
    float tv=x0[base+c];
    if (RES==1) tv+=resf[base+c];
    if (RES==2) tv+=resb[base+c];
    xv[i]=tv; s+=tv;
  }
  s = block_sum(s, sm);
  float m = s*(1.0f/768.0f);
  float vs=0.f;
  #pragma unroll
  for (int i=0;i<3;++i){ float d=xv[i]-m; vs+=d*d; }
  vs = block_sum(vs, sm);
  float inv = rsqrtf(vs*(1.0f/768.0f)+1e-5f);
  #pragma unroll
  for (int i=0;i<3;++i){
    int c=threadIdx.x+(i<<8);
    y[base+c]=(xv[i]-m)*inv*(g+gboff)[c]+(b+gboff)[c];
  }
}

__global__ void add_k(const float* __restrict__ a, const float* __restrict__ b, float* __restrict__ c, int n)
{ int i=blockIdx.x*256+threadIdx.x; if (i<n) c[i]=a[i]+b[i]; }

// ===== stage C screen: per row, per chunk, f32 top-24 candidate ids =====
__global__ __launch_bounds__(256)
void topk24_chunk_k(const float* __restrict__ simc, int* __restrict__ cand_id,
                    int off, int chunk, int cn, int ldc)
{
  __shared__ float sc_s[256*13];
  __shared__ int   id_s[256*13];
  int b=blockIdx.x, t=threadIdx.x;
  const float* rowp = simc + (size_t)b*ldc;
  float ls[13]; int li[13];
  #pragma unroll
  for (int k=0;k<13;++k){ ls[k]=-1e30f; li[k]=0x7fffffff; }
  for (int j=t;j<cn;j+=256){
    float sc = rowp[j];
    int id = off + j;
    if (sc > ls[12] || (sc == ls[12] && id < li[12])){
      int p=12;
      while (p>0 && (ls[p-1]<sc || (ls[p-1]==sc && li[p-1]>id))){
        ls[p]=ls[p-1]; li[p]=li[p-1]; --p;
      }
      ls[p]=sc; li[p]=id;
    }
  }
  #pragma unroll
  for (int k=0;k<13;++k){ sc_s[t*13+k]=ls[k]; id_s[t*13+k]=li[k]; }
  __syncthreads();
  if (t==0){
    float gs[CM_]; int gi[CM_];
    #pragma unroll
    for (int k=0;k<CM_;++k){ gs[k]=-1e30f; gi[k]=0x7fffffff; }
    for (int p=0;p<256*13;p+=13){
      for (int k=0;k<13;++k){
        float s=sc_s[p+k]; int id=id_s[p+k];
        bool better = (s>gs[CM_-1]) || (s==gs[CM_-1] && id<gi[CM_-1]);
        if (!better) break;
        int q=CM_-1;
        while (q>0 && (gs[q-1]<s || (gs[q-1]==s && gi[q-1]>id))){
          gs[q]=gs[q-1]; gi[q]=gi[q-1]; --q;
        }
        gs[q]=s; gi[q]=id;
      }
    }
    #pragma unroll
    for (int k=0;k<CM_;++k)
      cand_id[((size_t)b*NCH_+chunk)*CM_+k]=gi[k];
  }
}

// ===== f64 rescore of the 384 candidates/row -> exact top-10 ids =====
__global__ __launch_bounds__(256)
void rescore_k(const double* __restrict__ fproj64, const float* __restrict__ ans,
               const int* __restrict__ cand_id,
               const double* __restrict__ inv_fp64, const double* __restrict__ inv_an64,
               int* __restrict__ run_id)
{
  __shared__ double q[D_];
  __shared__ double sc_s[NCH_*CM_];
  __shared__ int    id_s[NCH_*CM_];
  int b = blockIdx.x, t = threadIdx.x;
  for (int i=t;i<D_;i+=256) q[i]=fproj64[(size_t)b*D_+i];
  __syncthreads();
  for (int c=t;c<NCH_*CM_;c+=256){
    int j = cand_id[(size_t)b*NCH_*CM_ + c];
    double s; int idout;
    if ((unsigned)j >= (unsigned)N_){ s = -1e300; idout = 0x7fffffff; }
    else {
      const float* ar = ans + (size_t)j*D_;
      double acc=0.0;
      for (int d=0;d<D_;++d) acc = fma(q[d], (double)ar[d], acc);
      s = acc * inv_fp64[b] * inv_an64[j];
      idout = j;
    }
    sc_s[c]=s; id_s[c]=idout;
  }
  __syncthreads();
  if (t==0){
    double gs[10]; int gi[10];
    #pragma unroll
    for (int k=0;k<10;++k){ gs[k]=-1e300; gi[k]=0x7fffffff; }
    for (int i=0;i<NCH_*CM_;++i){
      double s=sc_s[i]; int id=id_s[i];
      bool better9 = (s>gs[9]) || (s==gs[9] && id<gi[9]);
      if (!better9) continue;
      int q9=9;
      while (q9>0 && (gs[q9-1]<s || (gs[q9-1]==s && gi[q9-1]>id))){
        gs[q9]=gs[q9-1]; gi[q9]=gi[q9-1]; --q9;
      }
      gs[q9]=s; gi[q9]=id;
    }
    #pragma unroll
    for (int k=0;k<10;++k) run_id[b*10+k]=gi[k];
  }
}

// m4 attention: one thread per (b,h), f32.
__global__ __launch_bounds__(64)
void attn2_k(const float* __restrict__ qh, const float* __restrict__ kh,
             const float* __restrict__ vh, float* __restrict__ o)
{
  int idx = blockIdx.x*64 + threadIdx.x;
  if (idx >= B_*8) return;
  int b = idx >> 3, h = idx & 7;
  const float* q = qh + (size_t)b*D_ + h*96;
  float p[10];
  float mx = -1e30f;
  for (int j=0;j<10;++j){
    const float* kr = kh + ((size_t)(b*10+j))*D_ + h*96;
    float acc=0.f;
    for (int d=0;d<96;++d) acc = fmaf(q[d], kr[d], acc);
    p[j] = acc * 0.10206207261596575f;
    mx = fmaxf(mx, p[j]);
  }
  float sum=0.f;
  for (int j=0;j<10;++j){ p[j]=expf(p[j]-mx); sum+=p[j]; }
  float inv=1.0f/sum;
  for (int d=0;d<96;++d){
    float acc=0.f;
    for (int j=0;j<10;++j) acc = fmaf(p[j]*inv, vh[((size_t)(b*10+j))*D_ + h*96 + d], acc);
    o[(size_t)b*D_ + h*96 + d] = acc;
  }
}

extern "C" void kernel_launch(void* const* d_in, const int* in_sizes, int n_in,
                              void* d_out, int out_size, void* d_ws, size_t ws_size,
                              hipStream_t stream)
{
  const float* vis      = (const float*)d_in[0];
  const float* txt      = (const float*)d_in[1];
  const float* ans      = (const float*)d_in[2];
  const float* vqa_in_w = (const float*)d_in[3];
  const float* vqa_in_b = (const float*)d_in[4];
  const float* vqa_out_w= (const float*)d_in[5];
  const float* vqa_out_b= (const float*)d_in[6];
  const float* fproj_w  = (const float*)d_in[7];
  const float* fproj_b  = (const float*)d_in[8];
  const float* fln_g    = (const float*)d_in[9];
  const float* fln_b    = (const float*)d_in[10];
  const float* sim_w    = (const float*)d_in[11];
  const float* sim_b    = (const float*)d_in[12];
  const float* m_in_w   = (const float*)d_in[13];
  const float* m_in_b   = (const float*)d_in[14];
  const float* m_out_w  = (const float*)d_in[15];
  const float* m_out_b  = (const float*)d_in[16];
  const float* ffn_w1   = (const float*)d_in[17];
  const float* ffn_b1   = (const float*)d_in[18];
  const float* ffn_w2   = (const float*)d_in[19];
  const float* ffn_b2   = (const float*)d_in[20];
  const float* ln_g     = (const float*)d_in[21];
  const float* ln_b     = (const float*)d_in[22];
  const float* outp_w   = (const float*)d_in[23];
  const float* outp_b   = (const float*)d_in[24];
  const float* open_w1  = (const float*)d_in[25];
  const float* open_b1  = (const float*)d_in[26];
  const float* open_w2  = (const float*)d_in[27];
  const float* open_b2  = (const float*)d_in[28];
  (void)n_in; (void)out_size;

  if (in_sizes[0]!=B_*D_) return;
  if (in_sizes[1]!=B_*D_) return;
  if (in_sizes[2]!=N_*D_) return;
  if (in_sizes[3]!=3*D_*D_) return;
  if (in_sizes[4]!=3*D_) return;
  if (in_sizes[5]!=D_*D_) return;
  if (in_sizes[7]!=D_*2*D_) return;
  if (in_sizes[9]!=D_) return;
  if (in_sizes[13]!=5*3*D_*D_) return;
  if (in_sizes[14]!=5*3*D_) return;
  if (in_sizes[15]!=5*D_*D_) return;
  if (in_sizes[17]!=4*D_*D_) return;
  if (in_sizes[19]!=4*D_*D_) return;
  if (in_sizes[21]!=4*D_) return;
  if (in_sizes[23]!=D_*D_) return;
  if (in_sizes[25]!=D_*D_) return;
  if (in_sizes[27]!=N_*D_) return;

  const size_t MBc = (size_t)1<<20;
  if (ws_size < 84*MBc) return;
  char* base = (char*)d_ws;
  // ---- phase 1 (f64 selection chain) overlays ----
  double* attn_v64 = (double*)(base + 0);        // [0,6M)
  double* fusedin64= (double*)(base + 6*MBc);    // [6,18M)
  double* ta64     = (double*)(base + 18*MBc);   // [18,24M)
  double* fused64  = (double*)(base + 24*MBc);   // [24,30M)
  double* fproj64  = (double*)(base + 30*MBc);   // [30,36M)  persists through rescore
  float*  fproj32  = (float*) (base + 36*MBc);   // [36,39M)
  float*  sim_ch   = (float*) (base + 39*MBc);   // [39,51.8M)
  // ---- phase 2 (f32 residual stream) overlays (phase-1 dead when used) ----
  float* kh   = (float*)(base + 0);              // [0,30M)   m4
  float* vh   = (float*)(base + 30*MBc);         // [30,60M)  m4 (fproj64 dead post-rescore)
  float* h1   = (float*)(base + 0);              // [0,12M)   FFN (kh dead)
  float* t1   = (float*)(base + 60*MBc);         // m1->m2
  float* qh   = (float*)(base + 60*MBc);         // m4 (t1 dead)
  float* g1   = (float*)(base + 60*MBc);         // heads (qh dead)
  float* ta   = (float*)(base + 63*MBc);
  float* tb   = (float*)(base + 66*MBc);
  float* tc   = (float*)(base + 69*MBc);
  float* fz0  = (float*)(base + 69*MBc);         // after tc dead
  float* td   = (float*)(base + 72*MBc);
  float* fz   = (float*)(base + 72*MBc);         // after td dead
  float* v1   = (float*)(base + 75*MBc);         // m0->m3
  float* o4   = (float*)(base + 75*MBc);         // m4 (v1 dead)
  float* outv = (float*)(base + 75*MBc);         // heads (o4 dead)
  // ---- persistent tail [78,84M) ----
  double* inv_an64 = (double*)(base + 78*MBc);                 // 400KB
  double* inv_fp64 = (double*)(base + 78*MBc + 512*1024);      // 8KB
  float*  inv_an32 = (float*) (base + 78*MBc + 768*1024);      // 200KB
  float*  inv_fp32 = (float*) (base + 79*MBc);                 // 4KB
  int*    run_id   = (int*)   (base + 79*MBc + 256*1024);      // 40KB
  int*    cand_id  = (int*)   (base + 80*MBc);                 // 1.5MB

  dim3 blk(256);
  auto gg = [](int M,int N){ return dim3((unsigned)((N+63)/64),(unsigned)((M+63)/64)); };
  auto ng = [](int M,int N){ return dim3((unsigned)(((size_t)M*N+255)/256)); };
  const size_t IW = (size_t)2304*768, OW = (size_t)768*768;
  const size_t VOFF = (size_t)1536*768, KOFF = (size_t)768*768;
  const int* NORIDX = nullptr;
  const float* NOS = nullptr;

  // ======== phase 1: selection chain (f64 upstream, f32 screen, f64 rescore) ========
  prep64_k<<<ng(B_,D_), blk, 0, stream>>>(vis, fusedin64);
  dgemm_k<1,1><<<gg(B_,D_), blk, 0, stream>>>(vis, vqa_in_w, VOFF, vqa_in_b, 1536, attn_v64, B_, D_, D_, D_);
  dgemm_k<0,1><<<gg(B_,D_), blk, 0, stream>>>(attn_v64, vqa_out_w, 0, vqa_out_b, 0, fusedin64+D_, B_, D_, D_, 2*D_);
  dgemm_k<0,1><<<gg(B_,D_), blk, 0, stream>>>(fusedin64, fproj_w, 0, fproj_b, 0, ta64, B_, D_, 2*D_, D_);
  ln64_k<<<B_, blk, 0, stream>>>(ta64, fln_g, fln_b, fused64);
  dgemm_k<0,1><<<gg(B_,D_), blk, 0, stream>>>(fused64, sim_w, 0, sim_b, 0, fproj64, B_, D_, D_, D_);
  rnorm64_k<1><<<N_, blk, 0, stream>>>(ans, inv_an64);
  rnorm64_k<0><<<B_, blk, 0, stream>>>(fproj64, inv_fp64);
  d2f_k<<<(N_+255)/256, blk, 0, stream>>>(inv_an64, inv_an32, N_);
  d2f_k<<<(B_+255)/256, blk, 0, stream>>>(inv_fp64, inv_fp32, B_);
  d2f_k<<<(B_*D_+255)/256, blk, 0, stream>>>(fproj64, fproj32, B_*D_);
  for (int c=0;c<NCH_;++c){
    gemm_k<0,0,1><<<gg(B_,CH_), blk, 0, stream>>>(fproj32, NORIDX, ans, (size_t)c*CH_*D_, nullptr, 0, sim_ch, inv_fp32, inv_an32 + c*CH_, B_, CH_, D_, CH_);
    topk24_chunk_k<<<B_, blk, 0, stream>>>(sim_ch, cand_id, c*CH_, c, CH_, CH_);
  }
  rescore_k<<<B_, blk, 0, stream>>>(fproj64, ans, cand_id, inv_fp64, inv_an64, run_id);

  // ======== phase 2: residual stream (f32) ========
  gemm_k<2,1,0><<<gg(B_,D_), blk, 0, stream>>>(vis, NORIDX, m_in_w, 0*IW+VOFF, m_in_b, 0*2304+1536, ta, NOS, NOS, B_, D_, D_, D_);
  gemm_k<0,1,0><<<gg(B_,D_), blk, 0, stream>>>(ta, NORIDX, m_out_w, 0*OW, m_out_b, 0*768, tb, NOS, NOS, B_, D_, D_, D_);
  ln_k<2><<<B_, blk, 0, stream>>>(tb, nullptr, vis, ln_g, ln_b, 0*D_, v1);
  gemm_k<2,1,0><<<gg(B_,D_), blk, 0, stream>>>(txt, NORIDX, m_in_w, 1*IW+VOFF, m_in_b, 1*2304+1536, ta, NOS, NOS, B_, D_, D_, D_);
  gemm_k<0,1,0><<<gg(B_,D_), blk, 0, stream>>>(ta, NORIDX, m_out_w, 1*OW, m_out_b, 1*768, tb, NOS, NOS, B_, D_, D_, D_);
  ln_k<2><<<B_, blk, 0, stream>>>(tb, nullptr, txt, ln_g, ln_b, 1*D_, t1);
  gemm_k<0,1,0><<<gg(B_,D_), blk, 0, stream>>>(t1, NORIDX, m_in_w, 2*IW+VOFF, m_in_b, 2*2304+1536, ta, NOS, NOS, B_, D_, D_, D_);
  gemm_k<0,1,0><<<gg(B_,D_), blk, 0, stream>>>(ta, NORIDX, m_out_w, 2*OW, m_out_b, 2*768, tb, NOS, NOS, B_, D_, D_, D_);
  gemm_k<0,1,0><<<gg(B_,D_), blk, 0, stream>>>(v1, NORIDX, m_in_w, 3*IW+VOFF, m_in_b, 3*2304+1536, tc, NOS, NOS, B_, D_, D_, D_);
  gemm_k<0,1,0><<<gg(B_,D_), blk, 0, stream>>>(tc, NORIDX, m_out_w, 3*OW, m_out_b, 3*768, td, NOS, NOS, B_, D_, D_, D_);
  ln_k<1><<<B_, blk, 0, stream>>>(tb, td, nullptr, ln_g, ln_b, 2*D_, fz0);
  // m4 over top-10 ans rows (gathered in-GEMM via run_id)
  gemm_k<0,1,0><<<gg(B_,D_), blk, 0, stream>>>(fz0, NORIDX, m_in_w, 4*IW, m_in_b, 4*2304, qh, NOS, NOS, B_, D_, D_, D_);
  gemm_k<3,1,0><<<gg(B_*K_,D_), blk, 0, stream>>>(ans, run_id, m_in_w, 4*IW+KOFF, m_in_b, 4*2304+768, kh, NOS, NOS, B_*K_, D_, D_, D_);
  gemm_k<3,1,0><<<gg(B_*K_,D_), blk, 0, stream>>>(ans, run_id, m_in_w, 4*IW+VOFF, m_in_b, 4*2304+1536, vh, NOS, NOS, B_*K_, D_, D_, D_);
  attn2_k<<<(B_*8+63)/64, dim3(64), 0, stream>>>(qh, kh, vh, o4);
  gemm_k<0,1,0><<<gg(B_,D_), blk, 0, stream>>>(o4, NORIDX, m_out_w, 4*OW, m_out_b, 4*768, ta, NOS, NOS, B_, D_, D_, D_);
  ln_k<1><<<B_, blk, 0, stream>>>(fz0, ta, nullptr, ln_g, ln_b, 3*D_, fz);
  // FFN + heads
  gemm_k<0,2,0><<<gg(B_,4*D_), blk, 0, stream>>>(fz, NORIDX, ffn_w1, 0, ffn_b1, 0, h1, NOS, NOS, B_, 4*D_, D_, 4*D_);
  gemm_k<0,1,0><<<gg(B_,D_), blk, 0, stream>>>(h1, NORIDX, ffn_w2, 0, ffn_b2, 0, tb, NOS, NOS, B_, D_, 4*D_, D_);
  add_k<<<ng(B_,D_), blk, 0, stream>>>(fz, tb, ta, B_*D_);
  gemm_k<0,1,0><<<gg(B_,D_), blk, 0, stream>>>(ta, NORIDX, outp_w, 0, outp_b, 0, outv, NOS, NOS, B_, D_, D_, D_);
  gemm_k<0,2,0><<<gg(B_,D_), blk, 0, stream>>>(outv, NORIDX, open_w1, 0, open_b1, 0, g1, NOS, NOS, B_, D_, D_, D_);
  gemm_k<0,1,0><<<gg(B_,N_), blk, 0, stream>>>(g1, NORIDX, open_w2, 0, open_b2, 0, (float*)d_out, NOS, NOS, B_, N_, D_, N_);
}

// Round 12
// 4634.459 us; speedup vs baseline: 1.8591x; 1.8591x over previous
//
#include <hip/hip_runtime.h>
#include <hip/hip_bf16.h>

#define D_  768
#define B_  1024
#define N_  50000
#define K_  10
#define CH2_ 12500
#define NCH2_ 4
#define CM2_ 16
#define KPT_ 49   // ceil(12500/256)

__device__ __forceinline__ float gelu_f(float x){ return 0.5f*x*(1.0f+erff(x*0.70710678118654752f)); }
__device__ __forceinline__ double gelu_d(double x){ return 0.5*x*(1.0+erf(x*0.707106781186547524400844362105)); }

__device__ __forceinline__ float block_sum(float v, float* sm){
  #pragma unroll
  for (int o=32;o>0;o>>=1) v += __shfl_xor(v,o);
  __syncthreads();
  if ((threadIdx.x&63)==0) sm[threadIdx.x>>6]=v;
  __syncthreads();
  return (sm[0]+sm[1])+(sm[2]+sm[3]);
}
__device__ __forceinline__ double block_sum64(double v, double* sm){
  #pragma unroll
  for (int o=32;o>0;o>>=1) v += __shfl_xor(v,o);
  __syncthreads();
  if ((threadIdx.x&63)==0) sm[threadIdx.x>>6]=v;
  __syncthreads();
  return (sm[0]+sm[1])+(sm[2]+sm[3]);
}

// ============ f64 tiled GEMM (stage A/B): C = A @ W^T + bias ============
template<int ASRC, int EPI>
__global__ __launch_bounds__(256)
void dgemm_k(const void* __restrict__ Ap, const float* __restrict__ Wp, size_t woff,
             const float* __restrict__ biasp, size_t boff, double* __restrict__ Cp,
             int M, int N, int Kd, int ldc)
{
  __shared__ double As[16][64];
  __shared__ double Bs[16][64];
  const int t  = threadIdx.x;
  const int tx = t & 15, ty = t >> 4;
  const int row0 = blockIdx.y << 6, col0 = blockIdx.x << 6;
  const int lr = t >> 2, lk = (t & 3) << 2;
  const int ar = row0 + lr;
  const int wn = col0 + lr;
  const float* Wf = Wp + woff;
  double acc[4][4] = {};
  for (int k0 = 0; k0 < Kd; k0 += 16) {
    double av[4], wv[4];
    if (ar < M) {
      if (ASRC==0){
        const double* a = (const double*)Ap + (size_t)ar*Kd + k0 + lk;
        av[0]=a[0]; av[1]=a[1]; av[2]=a[2]; av[3]=a[3];
      } else {
        float4 v = *(const float4*)((const float*)Ap + (size_t)ar*Kd + k0 + lk);
        av[0]=(double)v.x; av[1]=(double)v.y; av[2]=(double)v.z; av[3]=(double)v.w;
      }
    } else { av[0]=av[1]=av[2]=av[3]=0.0; }
    if (wn < N) {
      float4 v = *(const float4*)(Wf + (size_t)wn*Kd + k0 + lk);
      wv[0]=(double)v.x; wv[1]=(double)v.y; wv[2]=(double)v.z; wv[3]=(double)v.w;
    } else { wv[0]=wv[1]=wv[2]=wv[3]=0.0; }
    #pragma unroll
    for (int u=0;u<4;++u){ As[lk+u][lr]=av[u]; Bs[lk+u][lr]=wv[u]; }
    __syncthreads();
    #pragma unroll
    for (int kk=0;kk<16;++kk){
      double aa[4], bb[4];
      #pragma unroll
      for (int u=0;u<4;++u){ aa[u]=As[kk][(ty<<2)+u]; bb[u]=Bs[kk][(tx<<2)+u]; }
      #pragma unroll
      for (int i=0;i<4;++i)
        #pragma unroll
        for (int j=0;j<4;++j)
          acc[i][j] = fma(aa[i], bb[j], acc[i][j]);
    }
    __syncthreads();
  }
  #pragma unroll
  for (int i=0;i<4;++i){
    int r=row0+(ty<<2)+i; if (r>=M) continue;
    #pragma unroll
    for (int j=0;j<4;++j){
      int n=col0+(tx<<2)+j; if (n>=N) continue;
      double v=acc[i][j];
      if (EPI) v += (double)(biasp+boff)[n];
      Cp[(size_t)r*ldc+n]=v;
    }
  }
}

// f64 LN + gelu (stage B)
__global__ __launch_bounds__(256)
void ln64_k(const double* __restrict__ x0, const float* __restrict__ g,
            const float* __restrict__ b, double* __restrict__ y)
{
  __shared__ double sm[4];
  size_t base = (size_t)blockIdx.x * D_;
  double xv[3]; double s=0.0;
  #pragma unroll
  for (int i=0;i<3;++i){ int c=threadIdx.x+(i<<8); xv[i]=x0[base+c]; s+=xv[i]; }
  s = block_sum64(s, sm);
  double m = s*(1.0/768.0);
  double vs=0.0;
  #pragma unroll
  for (int i=0;i<3;++i){ double d=xv[i]-m; vs+=d*d; }
  vs = block_sum64(vs, sm);
  double inv = 1.0/sqrt(vs*(1.0/768.0)+1e-5);
  #pragma unroll
  for (int i=0;i<3;++i){
    int c=threadIdx.x+(i<<8);
    double o=(xv[i]-m)*inv*(double)g[c]+(double)b[c];
    y[base+c]=gelu_d(o);
  }
}

// f64 inverse row norm, one WAVE per row.  SRC: 0 f64 ws, 1 f32 d_in.
template<int SRC>
__global__ __launch_bounds__(256)
void rnorm64w_k(const void* __restrict__ x, double* __restrict__ invn, int M)
{
  int gw = (blockIdx.x*256 + threadIdx.x) >> 6;
  int lane = threadIdx.x & 63;
  if (gw >= M) return;
  size_t base = (size_t)gw * D_;
  double s = 0.0;
  #pragma unroll
  for (int k=0;k<12;++k){
    double v = (SRC==1) ? (double)((const float*)x)[base+lane+(k<<6)]
                        : ((const double*)x)[base+lane+(k<<6)];
    s = fma(v,v,s);
  }
  #pragma unroll
  for (int o=32;o>0;o>>=1) s += __shfl_xor(s,o);
  if (lane==0) invn[gw] = 1.0/fmax(sqrt(s),1e-12);
}

__global__ void d2f_k(const double* __restrict__ src, float* __restrict__ dst, int n)
{ int i=blockIdx.x*256+threadIdx.x; if (i<n) dst[i]=(float)src[i]; }

__global__ void prep64_k(const float* __restrict__ vis, double* __restrict__ fusedin)
{
  int i = blockIdx.x*256+threadIdx.x;
  if (i >= B_*D_) return;
  int r=i/D_, c=i-r*D_;
  fusedin[(size_t)r*(2*D_)+c]=(double)vis[i];
}

// ============ f32 tiled GEMM ============
// ATY: 0 = A ws f32; 2 = A d_in f32; 3 = A d_in f32 with row gather.
// EPI: 0 none, 1 +bias, 2 +bias+gelu.  SCALE: epilogue ×inva32[r]×invw32[n].
template<int ATY, int EPI, int SCALE>
__global__ __launch_bounds__(256)
void gemm_k(const float* __restrict__ Ap, const int* __restrict__ ridx,
            const float* __restrict__ Wp, size_t woff,
            const float* __restrict__ biasp, size_t boff, float* __restrict__ Cp,
            const float* __restrict__ inva32, const float* __restrict__ invw32,
            int M, int N, int Kd, int ldc)
{
  __shared__ __align__(16) float As[16][64];
  __shared__ __align__(16) float Bs[16][64];
  const int t  = threadIdx.x;
  const int tx = t & 15, ty = t >> 4;
  const int row0 = blockIdx.y << 6, col0 = blockIdx.x << 6;
  const int lr = t >> 2, lk = (t & 3) << 2;
  const int ar = row0 + lr;
  const int wn = col0 + lr;
  const float* Wf = Wp + woff;
  float acc[4][4] = {};
  int arow = ar;
  if (ATY==3 && ar < M){
    arow = ridx[ar];
    if ((unsigned)arow >= (unsigned)N_) arow = 0;
  }
  for (int k0 = 0; k0 < Kd; k0 += 16) {
    float av[4], wv[4];
    if (ar < M) {
      float4 v = *(const float4*)(Ap + (size_t)arow*Kd + k0 + lk);
      av[0]=v.x; av[1]=v.y; av[2]=v.z; av[3]=v.w;
    } else { av[0]=av[1]=av[2]=av[3]=0.f; }
    if (wn < N) {
      float4 v = *(const float4*)(Wf + (size_t)wn*Kd + k0 + lk);
      wv[0]=v.x; wv[1]=v.y; wv[2]=v.z; wv[3]=v.w;
    } else { wv[0]=wv[1]=wv[2]=wv[3]=0.f; }
    #pragma unroll
    for (int u=0;u<4;++u){ As[lk+u][lr]=av[u]; Bs[lk+u][lr]=wv[u]; }
    __syncthreads();
    #pragma unroll
    for (int kk=0;kk<16;++kk){
      float4 a4 = *(const float4*)&As[kk][ty<<2];
      float4 b4 = *(const float4*)&Bs[kk][tx<<2];
      float aa[4]={a4.x,a4.y,a4.z,a4.w};
      float bb[4]={b4.x,b4.y,b4.z,b4.w};
      #pragma unroll
      for (int i=0;i<4;++i)
        #pragma unroll
        for (int j=0;j<4;++j)
          acc[i][j] = fmaf(aa[i], bb[j], acc[i][j]);
    }
    __syncthreads();
  }
  float bv[4];
  #pragma unroll
  for (int j=0;j<4;++j){
    int n=col0+(tx<<2)+j;
    bv[j] = (EPI>=1 && n<N) ? (biasp+boff)[n] : 0.f;
  }
  #pragma unroll
  for (int i=0;i<4;++i){
    int r=row0+(ty<<2)+i; if (r>=M) continue;
    float ia = (SCALE && r<M) ? inva32[r] : 1.f;
    #pragma unroll
    for (int j=0;j<4;++j){
      int n=col0+(tx<<2)+j; if (n>=N) continue;
      float v=acc[i][j]+bv[j];
      if (EPI==2) v=gelu_f(v);
      if (SCALE) v = v * ia * invw32[n];
      Cp[(size_t)r*ldc+n]=v;
    }
  }
}

// f32 LN
template<int RES>
__global__ __launch_bounds__(256)
void ln_k(const float* __restrict__ x0, const float* __restrict__ resf,
          const float* __restrict__ resb,
          const float* __restrict__ g, const float* __restrict__ b, size_t gboff,
          float* __restrict__ y)
{
  __shared__ float sm[4];
  size_t base = (size_t)blockIdx.x * D_;
  float xv[3]; float s=0.f;
  #pragma unroll
  for (int i=0;i<3;++i){
    int c=threadIdx.x+(i<<8);
    float tv=x0[base+c];
    if (RES==1) tv+=resf[base+c];
    if (RES==2) tv+=resb[base+c];
    xv[i]=tv; s+=tv;
  }
  s = block_sum(s, sm);
  float m = s*(1.0f/768.0f);
  float vs=0.f;
  #pragma unroll
  for (int i=0;i<3;++i){ float d=xv[i]-m; vs+=d*d; }
  vs = block_sum(vs, sm);
  float inv = rsqrtf(vs*(1.0f/768.0f)+1e-5f);
  #pragma unroll
  for (int i=0;i<3;++i){
    int c=threadIdx.x+(i<<8);
    y[base+c]=(xv[i]-m)*inv*(g+gboff)[c]+(b+gboff)[c];
  }
}

__global__ void add_k(const float* __restrict__ a, const float* __restrict__ b, float* __restrict__ c, int n)
{ int i=blockIdx.x*256+threadIdx.x; if (i<n) c[i]=a[i]+b[i]; }

// ===== stage C screen: per row-chunk, exact f32 top-16 via 16 parallel argmax rounds =====
__global__ __launch_bounds__(256)
void topk16_chunk_k(const float* __restrict__ simc, int* __restrict__ cand_id,
                    int off, int chunk, int cn, int ldc)
{
  __shared__ float rs[4];
  __shared__ int   ri[4];
  __shared__ float bs_s;
  __shared__ int   bi_s;
  int b = blockIdx.x, t = threadIdx.x;
  const float* rowp = simc + (size_t)b*ldc;
  float v[KPT_];
  #pragma unroll
  for (int k=0;k<KPT_;++k){
    int j = t + (k<<8);
    v[k] = (j < cn) ? rowp[j] : -1e30f;
  }
  float ps = 1e30f; int pi = -1;   // lexicographic threshold (prev extracted)
  for (int round=0; round<CM2_; ++round){
    float ms = -1e30f; int mi = 0x7fffffff;
    #pragma unroll
    for (int k=0;k<KPT_;++k){
      int j = t + (k<<8);
      float s = v[k];
      bool elig = (s < ps) || (s == ps && j > pi);
      if (elig && (s > ms || (s == ms && j < mi))){ ms = s; mi = j; }
    }
    #pragma unroll
    for (int o=32;o>0;o>>=1){
      float os = __shfl_xor(ms, o); int oi = __shfl_xor(mi, o);
      if (os > ms || (os == ms && oi < mi)){ ms = os; mi = oi; }
    }
    if ((t&63)==0){ rs[t>>6]=ms; ri[t>>6]=mi; }
    __syncthreads();
    if (t==0){
      float gs=rs[0]; int gi=ri[0];
      #pragma unroll
      for (int w=1;w<4;++w) if (rs[w]>gs || (rs[w]==gs && ri[w]<gi)){ gs=rs[w]; gi=ri[w]; }
      bs_s=gs; bi_s=gi;
      cand_id[((size_t)b*NCH2_+chunk)*CM2_+round] = (gi==0x7fffffff) ? 0x7fffffff : off+gi;
    }
    __syncthreads();
    ps = bs_s; pi = bi_s;
  }
}

// ===== f64 rescore, one WAVE per candidate (coalesced ans reads) =====
__global__ __launch_bounds__(256)
void rescore_k(const double* __restrict__ fproj64, const float* __restrict__ ans,
               const int* __restrict__ cand_id,
               const double* __restrict__ inv_fp64, const double* __restrict__ inv_an64,
               int* __restrict__ run_id)
{
  __shared__ double q[D_];
  __shared__ double sc_s[NCH2_*CM2_];
  __shared__ int    id_s[NCH2_*CM2_];
  int b = blockIdx.x, t = threadIdx.x;
  int wave = t>>6, lane = t&63;
  for (int i=t;i<D_;i+=256) q[i]=fproj64[(size_t)b*D_+i];
  __syncthreads();
  for (int c = wave; c < NCH2_*CM2_; c += 4){
    int j = cand_id[(size_t)b*NCH2_*CM2_ + c];
    bool ok = ((unsigned)j < (unsigned)N_);
    double acc = 0.0;
    if (ok){
      const float* ar = ans + (size_t)j*D_;
      #pragma unroll
      for (int k=0;k<12;++k){
        int d = lane + (k<<6);
        acc = fma(q[d], (double)ar[d], acc);
      }
    }
    #pragma unroll
    for (int o=32;o>0;o>>=1) acc += __shfl_xor(acc, o);
    if (lane==0){
      sc_s[c] = ok ? acc*inv_fp64[b]*inv_an64[j] : -1e300;
      id_s[c] = ok ? j : 0x7fffffff;
    }
  }
  __syncthreads();
  if (t==0){
    double gs[10]; int gi[10];
    #pragma unroll
    for (int k=0;k<10;++k){ gs[k]=-1e300; gi[k]=0x7fffffff; }
    for (int i=0;i<NCH2_*CM2_;++i){
      double s=sc_s[i]; int id=id_s[i];
      bool better9 = (s>gs[9]) || (s==gs[9] && id<gi[9]);
      if (!better9) continue;
      int q9=9;
      while (q9>0 && (gs[q9-1]<s || (gs[q9-1]==s && gi[q9-1]>id))){
        gs[q9]=gs[q9-1]; gi[q9]=gi[q9-1]; --q9;
      }
      gs[q9]=s; gi[q9]=id;
    }
    #pragma unroll
    for (int k=0;k<10;++k) run_id[b*10+k]=gi[k];
  }
}

// m4 attention: one thread per (b,h); K/V interleaved in kvh [B*10][1536].
__global__ __launch_bounds__(64)
void attn2_k(const float* __restrict__ qh, const float* __restrict__ kvh,
             float* __restrict__ o)
{
  int idx = blockIdx.x*64 + threadIdx.x;
  if (idx >= B_*8) return;
  int b = idx >> 3, h = idx & 7;
  const float* q = qh + (size_t)b*D_ + h*96;
  float p[10];
  float mx = -1e30f;
  for (int j=0;j<10;++j){
    const float* kr = kvh + ((size_t)(b*10+j))*1536 + h*96;
    float acc=0.f;
    for (int d=0;d<96;++d) acc = fmaf(q[d], kr[d], acc);
    p[j] = acc * 0.10206207261596575f;
    mx = fmaxf(mx, p[j]);
  }
  float sum=0.f;
  for (int j=0;j<10;++j){ p[j]=expf(p[j]-mx); sum+=p[j]; }
  float inv=1.0f/sum;
  for (int d=0;d<96;++d){
    float acc=0.f;
    for (int j=0;j<10;++j) acc = fmaf(p[j]*inv, kvh[((size_t)(b*10+j))*1536 + 768 + h*96 + d], acc);
    o[(size_t)b*D_ + h*96 + d] = acc;
  }
}

extern "C" void kernel_launch(void* const* d_in, const int* in_sizes, int n_in,
                              void* d_out, int out_size, void* d_ws, size_t ws_size,
                              hipStream_t stream)
{
  const float* vis      = (const float*)d_in[0];
  const float* txt      = (const float*)d_in[1];
  const float* ans      = (const float*)d_in[2];
  const float* vqa_in_w = (const float*)d_in[3];
  const float* vqa_in_b = (const float*)d_in[4];
  const float* vqa_out_w= (const float*)d_in[5];
  const float* vqa_out_b= (const float*)d_in[6];
  const float* fproj_w  = (const float*)d_in[7];
  const float* fproj_b  = (const float*)d_in[8];
  const float* fln_g    = (const float*)d_in[9];
  const float* fln_b    = (const float*)d_in[10];
  const float* sim_w    = (const float*)d_in[11];
  const float* sim_b    = (const float*)d_in[12];
  const float* m_in_w   = (const float*)d_in[13];
  const float* m_in_b   = (const float*)d_in[14];
  const float* m_out_w  = (const float*)d_in[15];
  const float* m_out_b  = (const float*)d_in[16];
  const float* ffn_w1   = (const float*)d_in[17];
  const float* ffn_b1   = (const float*)d_in[18];
  const float* ffn_w2   = (const float*)d_in[19];
  const float* ffn_b2   = (const float*)d_in[20];
  const float* ln_g     = (const float*)d_in[21];
  const float* ln_b     = (const float*)d_in[22];
  const float* outp_w   = (const float*)d_in[23];
  const float* outp_b   = (const float*)d_in[24];
  const float* open_w1  = (const float*)d_in[25];
  const float* open_b1  = (const float*)d_in[26];
  const float* open_w2  = (const float*)d_in[27];
  const float* open_b2  = (const float*)d_in[28];
  (void)n_in; (void)out_size;

  if (in_sizes[0]!=B_*D_) return;
  if (in_sizes[1]!=B_*D_) return;
  if (in_sizes[2]!=N_*D_) return;
  if (in_sizes[3]!=3*D_*D_) return;
  if (in_sizes[4]!=3*D_) return;
  if (in_sizes[5]!=D_*D_) return;
  if (in_sizes[7]!=D_*2*D_) return;
  if (in_sizes[9]!=D_) return;
  if (in_sizes[13]!=5*3*D_*D_) return;
  if (in_sizes[14]!=5*3*D_) return;
  if (in_sizes[15]!=5*D_*D_) return;
  if (in_sizes[17]!=4*D_*D_) return;
  if (in_sizes[19]!=4*D_*D_) return;
  if (in_sizes[21]!=4*D_) return;
  if (in_sizes[23]!=D_*D_) return;
  if (in_sizes[25]!=D_*D_) return;
  if (in_sizes[27]!=N_*D_) return;

  const size_t MBc = (size_t)1<<20;
  if (ws_size < 84*MBc) return;
  char* base = (char*)d_ws;
  // ---- phase 1 (f64 selection chain) ----
  double* fusedin64 = (double*)(base + 0);       // [0,12M)
  double* attn_v64  = (double*)(base + 12*MBc);  // [12,18M)
  double* ta64      = (double*)(base + 12*MBc);  // [12,18M) (attn_v64 dead)
  double* fused64   = (double*)(base + 18*MBc);  // [18,24M)
  double* fproj64   = (double*)(base + 60*MBc);  // [60,66M) persists -> rescore
  float*  fproj32   = (float*) (base + 66*MBc);  // [66,69M)
  float*  sim_ch    = (float*) (base + 0);       // [0,51.2M) screen (A/B temps dead)
  double* inv_an64  = (double*)(base + 69*MBc);  // 400KB
  double* inv_fp64  = (double*)(base + 70*MBc);  // 8KB
  float*  inv_an32  = (float*) (base + 71*MBc);  // 200KB
  float*  inv_fp32  = (float*) (base + 72*MBc);  // 4KB
  int*    cand_id   = (int*)   (base + 73*MBc);  // 256KB
  int*    run_id    = (int*)   (base + 78*MBc);  // 40KB (survives into phase 2)
  // ---- phase 2 (f32 residual stream; phase-1 regions dead) ----
  float* kvh  = (float*)(base + 0);              // [0,60M)   m4 K|V
  float* h1   = (float*)(base + 0);              // [0,12M)   FFN (kvh dead)
  float* ta   = (float*)(base + 60*MBc);         // [60,63M)
  float* tb   = (float*)(base + 63*MBc);         // [63,66M)
  float* tc   = (float*)(base + 66*MBc);         // [66,69M)
  float* fz0  = (float*)(base + 66*MBc);         // (tc dead)
  float* td   = (float*)(base + 69*MBc);         // [69,72M)
  float* fz   = (float*)(base + 69*MBc);         // (td dead)
  float* v1   = (float*)(base + 72*MBc);         // [72,75M) m0->m3
  float* o4   = (float*)(base + 72*MBc);         // m4 (v1 dead)
  float* outv = (float*)(base + 72*MBc);         // heads (o4 dead)
  float* t1   = (float*)(base + 75*MBc);         // [75,78M) m1->m2
  float* qh   = (float*)(base + 75*MBc);         // m4 (t1 dead)
  float* g1   = (float*)(base + 75*MBc);         // heads (qh dead)

  dim3 blk(256);
  auto gg = [](int M,int N){ return dim3((unsigned)((N+63)/64),(unsigned)((M+63)/64)); };
  auto ng = [](int M,int N){ return dim3((unsigned)(((size_t)M*N+255)/256)); };
  const size_t IW = (size_t)2304*768, OW = (size_t)768*768;
  const size_t VOFF = (size_t)1536*768, KOFF = (size_t)768*768;
  const int* NORIDX = nullptr;
  const float* NOS = nullptr;

  // ======== phase 1: selection (f64 chain, f32 screen, f64 rescore) ========
  prep64_k<<<ng(B_,D_), blk, 0, stream>>>(vis, fusedin64);
  dgemm_k<1,1><<<gg(B_,D_), blk, 0, stream>>>(vis, vqa_in_w, VOFF, vqa_in_b, 1536, attn_v64, B_, D_, D_, D_);
  dgemm_k<0,1><<<gg(B_,D_), blk, 0, stream>>>(attn_v64, vqa_out_w, 0, vqa_out_b, 0, fusedin64+D_, B_, D_, D_, 2*D_);
  dgemm_k<0,1><<<gg(B_,D_), blk, 0, stream>>>(fusedin64, fproj_w, 0, fproj_b, 0, ta64, B_, D_, 2*D_, D_);
  ln64_k<<<B_, blk, 0, stream>>>(ta64, fln_g, fln_b, fused64);
  dgemm_k<0,1><<<gg(B_,D_), blk, 0, stream>>>(fused64, sim_w, 0, sim_b, 0, fproj64, B_, D_, D_, D_);
  rnorm64w_k<1><<<(N_*64+255)/256, blk, 0, stream>>>(ans, inv_an64, N_);
  rnorm64w_k<0><<<(B_*64+255)/256, blk, 0, stream>>>(fproj64, inv_fp64, B_);
  d2f_k<<<(N_+255)/256, blk, 0, stream>>>(inv_an64, inv_an32, N_);
  d2f_k<<<(B_+255)/256, blk, 0, stream>>>(inv_fp64, inv_fp32, B_);
  d2f_k<<<(B_*D_+255)/256, blk, 0, stream>>>(fproj64, fproj32, B_*D_);
  for (int c=0;c<NCH2_;++c){
    gemm_k<0,0,1><<<gg(B_,CH2_), blk, 0, stream>>>(fproj32, NORIDX, ans, (size_t)c*CH2_*D_, nullptr, 0, sim_ch, inv_fp32, inv_an32 + c*CH2_, B_, CH2_, D_, CH2_);
    topk16_chunk_k<<<B_, blk, 0, stream>>>(sim_ch, cand_id, c*CH2_, c, CH2_, CH2_);
  }
  rescore_k<<<B_, blk, 0, stream>>>(fproj64, ans, cand_id, inv_fp64, inv_an64, run_id);

  // ======== phase 2: residual stream (f32) ========
  gemm_k<2,1,0><<<gg(B_,D_), blk, 0, stream>>>(vis, NORIDX, m_in_w, 0*IW+VOFF, m_in_b, 0*2304+1536, ta, NOS, NOS, B_, D_, D_, D_);
  gemm_k<0,1,0><<<gg(B_,D_), blk, 0, stream>>>(ta, NORIDX, m_out_w, 0*OW, m_out_b, 0*768, tb, NOS, NOS, B_, D_, D_, D_);
  ln_k<2><<<B_, blk, 0, stream>>>(tb, nullptr, vis, ln_g, ln_b, 0*D_, v1);
  gemm_k<2,1,0><<<gg(B_,D_), blk, 0, stream>>>(txt, NORIDX, m_in_w, 1*IW+VOFF, m_in_b, 1*2304+1536, ta, NOS, NOS, B_, D_, D_, D_);
  gemm_k<0,1,0><<<gg(B_,D_), blk, 0, stream>>>(ta, NORIDX, m_out_w, 1*OW, m_out_b, 1*768, tb, NOS, NOS, B_, D_, D_, D_);
  ln_k<2><<<B_, blk, 0, stream>>>(tb, nullptr, txt, ln_g, ln_b, 1*D_, t1);
  gemm_k<0,1,0><<<gg(B_,D_), blk, 0, stream>>>(t1, NORIDX, m_in_w, 2*IW+VOFF, m_in_b, 2*2304+1536, ta, NOS, NOS, B_, D_, D_, D_);
  gemm_k<0,1,0><<<gg(B_,D_), blk, 0, stream>>>(ta, NORIDX, m_out_w, 2*OW, m_out_b, 2*768, tb, NOS, NOS, B_, D_, D_, D_);
  gemm_k<0,1,0><<<gg(B_,D_), blk, 0, stream>>>(v1, NORIDX, m_in_w, 3*IW+VOFF, m_in_b, 3*2304+1536, tc, NOS, NOS, B_, D_, D_, D_);
  gemm_k<0,1,0><<<gg(B_,D_), blk, 0, stream>>>(tc, NORIDX, m_out_w, 3*OW, m_out_b, 3*768, td, NOS, NOS, B_, D_, D_, D_);
  ln_k<1><<<B_, blk, 0, stream>>>(tb, td, nullptr, ln_g, ln_b, 2*D_, fz0);
  // m4: q proj + fused K|V proj over gathered ans rows + attention
  gemm_k<0,1,0><<<gg(B_,D_), blk, 0, stream>>>(fz0, NORIDX, m_in_w, 4*IW, m_in_b, 4*2304, qh, NOS, NOS, B_, D_, D_, D_);
  gemm_k<3,1,0><<<gg(B_*K_,2*D_), blk, 0, stream>>>(ans, run_id, m_in_w, 4*IW+KOFF, m_in_b, 4*2304+768, kvh, NOS, NOS, B_*K_, 2*D_, D_, 2*D_);
  attn2_k<<<(B_*8+63)/64, dim3(64), 0, stream>>>(qh, kvh, o4);
  gemm_k<0,1,0><<<gg(B_,D_), blk, 0, stream>>>(o4, NORIDX, m_out_w, 4*OW, m_out_b, 4*768, ta, NOS, NOS, B_, D_, D_, D_);
  ln_k<1><<<B_, blk, 0, stream>>>(fz0, ta, nullptr, ln_g, ln_b, 3*D_, fz);
  // FFN + heads
  gemm_k<0,2,0><<<gg(B_,4*D_), blk, 0, stream>>>(fz, NORIDX, ffn_w1, 0, ffn_b1, 0, h1, NOS, NOS, B_, 4*D_, D_, 4*D_);
  gemm_k<0,1,0><<<gg(B_,D_), blk, 0, stream>>>(h1, NORIDX, ffn_w2, 0, ffn_b2, 0, tb, NOS, NOS, B_, D_, 4*D_, D_);
  add_k<<<ng(B_,D_), blk, 0, stream>>>(fz, tb, ta, B_*D_);
  gemm_k<0,1,0><<<gg(B_,D_), blk, 0, stream>>>(ta, NORIDX, outp_w, 0, outp_b, 0, outv, NOS, NOS, B_, D_, D_, D_);
  gemm_k<0,2,0><<<gg(B_,D_), blk, 0, stream>>>(outv, NORIDX, open_w1, 0, open_b1, 0, g1, NOS, NOS, B_, D_, D_, D_);
  gemm_k<0,1,0><<<gg(B_,N_), blk, 0, stream>>>(g1, NORIDX, open_w2, 0, open_b2, 0, (float*)d_out, NOS, NOS, B_, N_, D_, N_);
}